// Round 12
// baseline (3622.971 us; speedup 1.0000x reference)
//
#include <hip/hip_runtime.h>

typedef unsigned int u32;
typedef unsigned short u16;
typedef unsigned long long u64;
typedef __attribute__((ext_vector_type(8))) short v8s;   // 8 bf16
typedef __attribute__((ext_vector_type(4))) float v4f;

#define VALIDMASK 0x0001000100010001ULL

__device__ __forceinline__ float bf2f(u16 v) { return __uint_as_float(((u32)v) << 16); }
__device__ __forceinline__ u16 f2bf(float f) {
    u32 u = __float_as_uint(f);
    return (u16)((u + 0x7fffu + ((u >> 16) & 1u)) >> 16);   // RNE
}
// truncate-to-odd bf16: LSB always 1 (valid bit), |err| <= 1 ulp
__device__ __forceinline__ u32 f2bfo(float f) { return (__float_as_uint(f) >> 16) | 1u; }
__device__ __forceinline__ float sigf(float x) { return 1.0f / (1.0f + __expf(-x)); }
__device__ __forceinline__ float tanhfast(float x) {
    float e = __expf(2.0f * x);
    return 1.0f - 2.0f / (e + 1.0f);
}
__device__ __forceinline__ v8s pack8(v4f a, v4f b) {
    v8s r;
    r[0] = (short)f2bf(a[0]); r[1] = (short)f2bf(a[1]);
    r[2] = (short)f2bf(a[2]); r[3] = (short)f2bf(a[3]);
    r[4] = (short)f2bf(b[0]); r[5] = (short)f2bf(b[1]);
    r[6] = (short)f2bf(b[2]); r[7] = (short)f2bf(b[3]);
    return r;
}

// ---------------------------------------------------------------------------
// GEMM: out[t][j] = sum_k A[t][k]*W[j][k] + bih[j] + bhh[j]. fp32 in, bf16 out.
// Layer-0 input projections only (K=768).
// ---------------------------------------------------------------------------
__global__ __launch_bounds__(256) void gemm_ih(
    const float* __restrict__ A, const float* __restrict__ W,
    const float* __restrict__ bih, const float* __restrict__ bhh,
    u16* __restrict__ out, int K)
{
    __shared__ u16 As[128][40];
    __shared__ u16 Bs[128][40];
    const int tm = blockIdx.x, tn = blockIdx.y;
    const int tid = threadIdx.x;
    const int lane = tid & 63;
    const int wv = tid >> 6;
    const int wm = wv >> 1, wn = wv & 1;
    const int fr = lane & 15, fq = lane >> 4;

    v4f acc[4][4] = {};

    for (int kt = 0; kt < K; kt += 32) {
#pragma unroll
        for (int it = 0; it < 2; ++it) {
            int q = tid + it * 256;
            int r = q >> 2;
            int c8 = (q & 3) * 8;
            const float* pa = &A[(size_t)(tm * 128 + r) * K + kt + c8];
            const float* pw = &W[(size_t)(tn * 128 + r) * K + kt + c8];
            *(v8s*)&As[r][c8] = pack8(*(const v4f*)pa, *(const v4f*)(pa + 4));
            *(v8s*)&Bs[r][c8] = pack8(*(const v4f*)pw, *(const v4f*)(pw + 4));
        }
        __syncthreads();
        v8s af[4], bfr[4];
#pragma unroll
        for (int mi = 0; mi < 4; ++mi)
            af[mi] = *(const v8s*)&As[wm * 64 + mi * 16 + fr][fq * 8];
#pragma unroll
        for (int ni = 0; ni < 4; ++ni)
            bfr[ni] = *(const v8s*)&Bs[wn * 64 + ni * 16 + fr][fq * 8];
#pragma unroll
        for (int mi = 0; mi < 4; ++mi)
#pragma unroll
            for (int ni = 0; ni < 4; ++ni)
                acc[mi][ni] = __builtin_amdgcn_mfma_f32_16x16x32_bf16(af[mi], bfr[ni], acc[mi][ni], 0, 0, 0);
        __syncthreads();
    }

#pragma unroll
    for (int ni = 0; ni < 4; ++ni) {
        int col = tn * 128 + wn * 64 + ni * 16 + fr;
        float bias = bih[col] + bhh[col];
#pragma unroll
        for (int mi = 0; mi < 4; ++mi)
#pragma unroll
            for (int j = 0; j < 4; ++j) {
                int row = tm * 128 + wm * 64 + mi * 16 + fq * 4 + j;
                out[(size_t)row * 4096 + col] = f2bf(acc[mi][ni][j] + bias);
            }
    }
}

// ---------------------------------------------------------------------------
// Fused persistent bidirectional 2-layer LSTM scan. 512 WGs x 64 threads
// (1 wave per WG, no barriers). role = bid>>8 (0:L0, 1:L1), d = (bid>>7)&1,
// wg = bid&127, e0 = wg*8 (8 h-elements = 32 Whh rows).
// Whh: 256 VGPRs of pre-packed 16x16x32 A-fragments. L1's Wih1: LDS in
// fragment-contiguous layout off = c*2048+q*512+t*256+r0*16 (conflict-free
// ds_read_b128: each wave reads 1024B contiguous per k-chunk).
// h staging: lane i owns u64s {i,i+64,i+128,i+192} -> 8B-stride ds_writes
// (conflict-free). Broadcast: 4 odd-LSB bf16/u64, relaxed agent atomics.
// ---------------------------------------------------------------------------
__global__ __launch_bounds__(64, 1) void lstm_fused(
    const float* __restrict__ fw0_Whh, const float* __restrict__ bw0_Whh,
    const float* __restrict__ fw1_Whh, const float* __restrict__ bw1_Whh,
    const float* __restrict__ fw1_Wih, const float* __restrict__ bw1_Wih,
    const float* __restrict__ fw1_bih, const float* __restrict__ fw1_bhh,
    const float* __restrict__ bw1_bih, const float* __restrict__ bw1_bhh,
    const u16*  __restrict__ precomp0,   // [2][1024][4096] bf16
    u64* htag0,                          // [2][1024][256]
    u64* htag1,                          // [2][1024][256]
    float* __restrict__ out)             // d_out base
{
    extern __shared__ char smem[];       // [0,64K): Wih frags (L1)
    char* hA = smem + 65536;             // 2 KB own-layer h
    char* hB = smem + 65536 + 2048;      // 2 KB h0 input (L1)
    float* gd = (float*)(smem + 65536 + 4096);   // 32 gate sums

    const int lane = threadIdx.x;
    const int bid = blockIdx.x;
    const int role = bid >> 8;
    const int sub = bid & 255;
    const int d = sub >> 7;
    const int wg = sub & 127;
    const int e0 = wg << 3;
    const int q16 = (lane >> 4) << 4;    // B-frag byte offset within 64B block

    const float* __restrict__ Whh =
        role ? (d ? bw1_Whh : fw1_Whh) : (d ? bw0_Whh : fw0_Whh);

    // ---- Whh -> 64 A-fragments in registers (2 tiles x 32 K-chunks) ----
    v8s awf0[32], awf1[32];
    {
        int r0 = lane & 15, r1 = r0 + 16;
        int kq = (lane >> 4) << 3;
        const float* p0 = &Whh[(size_t)((r0 >> 3) * 1024 + e0 + (r0 & 7)) * 1024 + kq];
        const float* p1 = &Whh[(size_t)((r1 >> 3) * 1024 + e0 + (r1 & 7)) * 1024 + kq];
#pragma unroll
        for (int c = 0; c < 32; ++c) {
            awf0[c] = pack8(*(const v4f*)(p0 + 32 * c), *(const v4f*)(p0 + 32 * c + 4));
            awf1[c] = pack8(*(const v4f*)(p1 + 32 * c), *(const v4f*)(p1 + 32 * c + 4));
        }
    }

    // ---- L1: Wih1 -> LDS fragment-contiguous (BOTH column halves); biases ----
    float bias_i = 0.f, bias_f = 0.f, bias_g = 0.f, bias_o = 0.f;
    if (role) {
        const float* __restrict__ Wih = d ? bw1_Wih : fw1_Wih;
        // Matrix row i (0..31) = (gate i>>3, elem i&7); frag tile t=i>>4,
        // frag row r0=i&15. Lane covers cols lane*8 (k-chunk c=lane>>2) AND
        // cols 512+lane*8 (k-chunk c=16+(lane>>2)); q=lane&3.
        // off(c,q,t,r0) = c*2048 + q*512 + t*256 + r0*16.
        for (int i = 0; i < 32; ++i) {
            const float* prow = &Wih[(size_t)((i >> 3) * 1024 + e0 + (i & 7)) * 1024];
            int base = ((lane & 3) << 9) + ((i >> 4) << 8) + ((i & 15) << 4);
            const float* p0 = prow + lane * 8;
            const float* p1 = prow + 512 + lane * 8;
            *(v8s*)(smem + ((lane >> 2) << 11) + base) =
                pack8(*(const v4f*)p0, *(const v4f*)(p0 + 4));
            *(v8s*)(smem + ((16 + (lane >> 2)) << 11) + base) =
                pack8(*(const v4f*)p1, *(const v4f*)(p1 + 4));
        }
        if (lane < 8) {
            const float* bi = d ? bw1_bih : fw1_bih;
            const float* bh = d ? bw1_bhh : fw1_bhh;
            bias_i = bi[e0 + lane]        + bh[e0 + lane];
            bias_f = bi[1024 + e0 + lane] + bh[1024 + e0 + lane];
            bias_g = bi[2048 + e0 + lane] + bh[2048 + e0 + lane];
            bias_o = bi[3072 + e0 + lane] + bh[3072 + e0 + lane];
        }
    }

    u64* hown = (role ? htag1 : htag0) + (size_t)d * 1024 * 256;
    u64* hin  = htag0 + (size_t)d * 1024 * 256;
    float* cm_out = out + role * 2048;
    float* hs_out = out + 4096 + role * 2048;
    float* seq_out = out + 8192;                 // [1024][2048], L1 writes

    float c_state = 0.0f;                        // lanes 0..7 own elem e0+lane

    for (int s = 0; s < 1024; ++s) {
        v4f acc0a = {0.f,0.f,0.f,0.f}, acc0b = {0.f,0.f,0.f,0.f};
        v4f acc1a = {0.f,0.f,0.f,0.f}, acc1b = {0.f,0.f,0.f,0.f};

        // L0: prefetch precomp row early (hides under poll)
        u16 ri = 0, rf = 0, rg = 0, ro = 0;
        if (!role && lane < 8) {
            int sx = d ? (1023 - s) : s;
            const u16* pr = precomp0 + ((size_t)d * 1024 + sx) * 4096 + e0 + lane;
            ri = pr[0]; rf = pr[1024]; rg = pr[2048]; ro = pr[3072];
        }

        if (role) {   // ---- Wih1 @ h0[s] (h0 ready once L1 lags L0) ----
            u64* p = hin + (size_t)s * 256 + lane;
            u64 a, b, c2, d2;
            for (;;) {
                a  = __hip_atomic_load(&p[0],   __ATOMIC_RELAXED, __HIP_MEMORY_SCOPE_AGENT);
                b  = __hip_atomic_load(&p[64],  __ATOMIC_RELAXED, __HIP_MEMORY_SCOPE_AGENT);
                c2 = __hip_atomic_load(&p[128], __ATOMIC_RELAXED, __HIP_MEMORY_SCOPE_AGENT);
                d2 = __hip_atomic_load(&p[192], __ATOMIC_RELAXED, __HIP_MEMORY_SCOPE_AGENT);
                if ((((a & b) & (c2 & d2)) & VALIDMASK) == VALIDMASK) break;
                __builtin_amdgcn_s_sleep(1);
            }
            __builtin_amdgcn_s_setprio(1);
            *(u64*)(hB + (lane << 3))        = a;
            *(u64*)(hB + (lane << 3) + 512)  = b;
            *(u64*)(hB + (lane << 3) + 1024) = c2;
            *(u64*)(hB + (lane << 3) + 1536) = d2;
            asm volatile("s_waitcnt lgkmcnt(0)" ::: "memory");
            const int fb = ((lane >> 4) << 9) + ((lane & 15) << 4);  // q*512+r0*16
#pragma unroll
            for (int c = 0; c < 32; c += 2) {
                v8s b0 = *(const v8s*)(hB + (c << 6) + q16);
                v8s b1 = *(const v8s*)(hB + ((c + 1) << 6) + q16);
                v8s a00 = *(const v8s*)(smem + (c << 11) + fb);
                v8s a01 = *(const v8s*)(smem + (c << 11) + fb + 256);
                v8s a10 = *(const v8s*)(smem + ((c + 1) << 11) + fb);
                v8s a11 = *(const v8s*)(smem + ((c + 1) << 11) + fb + 256);
                acc0a = __builtin_amdgcn_mfma_f32_16x16x32_bf16(a00, b0, acc0a, 0, 0, 0);
                acc1a = __builtin_amdgcn_mfma_f32_16x16x32_bf16(a01, b0, acc1a, 0, 0, 0);
                acc0b = __builtin_amdgcn_mfma_f32_16x16x32_bf16(a10, b1, acc0b, 0, 0, 0);
                acc1b = __builtin_amdgcn_mfma_f32_16x16x32_bf16(a11, b1, acc1b, 0, 0, 0);
            }
            __builtin_amdgcn_s_setprio(0);
        }

        if (s > 0) {  // ---- Whh @ h_own[s-1] (the critical recurrence) ----
            u64* p = hown + (size_t)(s - 1) * 256 + lane;
            u64 a, b, c2, d2;
            for (;;) {
                a  = __hip_atomic_load(&p[0],   __ATOMIC_RELAXED, __HIP_MEMORY_SCOPE_AGENT);
                b  = __hip_atomic_load(&p[64],  __ATOMIC_RELAXED, __HIP_MEMORY_SCOPE_AGENT);
                c2 = __hip_atomic_load(&p[128], __ATOMIC_RELAXED, __HIP_MEMORY_SCOPE_AGENT);
                d2 = __hip_atomic_load(&p[192], __ATOMIC_RELAXED, __HIP_MEMORY_SCOPE_AGENT);
                if ((((a & b) & (c2 & d2)) & VALIDMASK) == VALIDMASK) break;
                __builtin_amdgcn_s_sleep(1);
            }
            __builtin_amdgcn_s_setprio(1);
            *(u64*)(hA + (lane << 3))        = a;
            *(u64*)(hA + (lane << 3) + 512)  = b;
            *(u64*)(hA + (lane << 3) + 1024) = c2;
            *(u64*)(hA + (lane << 3) + 1536) = d2;
            asm volatile("s_waitcnt lgkmcnt(0)" ::: "memory");
#pragma unroll
            for (int c = 0; c < 32; c += 2) {
                v8s b0 = *(const v8s*)(hA + (c << 6) + q16);
                v8s b1 = *(const v8s*)(hA + ((c + 1) << 6) + q16);
                acc0a = __builtin_amdgcn_mfma_f32_16x16x32_bf16(awf0[c], b0, acc0a, 0, 0, 0);
                acc1a = __builtin_amdgcn_mfma_f32_16x16x32_bf16(awf1[c], b0, acc1a, 0, 0, 0);
                acc0b = __builtin_amdgcn_mfma_f32_16x16x32_bf16(awf0[c + 1], b1, acc0b, 0, 0, 0);
                acc1b = __builtin_amdgcn_mfma_f32_16x16x32_bf16(awf1[c + 1], b1, acc1b, 0, 0, 0);
            }
            __builtin_amdgcn_s_setprio(0);
        }

        // ---- combine acc pairs; D col0 lanes dump 32 gate sums ----
        v4f acc0 = acc0a + acc0b;
        v4f acc1 = acc1a + acc1b;
        if ((lane & 15) == 0) {
            int rbase = (lane >> 4) << 2;        // 0,4,8,12
            *(v4f*)&gd[rbase]      = acc0;       // rows 0..15  (i, f)
            *(v4f*)&gd[16 + rbase] = acc1;       // rows 16..31 (g, o)
        }
        asm volatile("s_waitcnt lgkmcnt(0)" ::: "memory");

        float h_new = 0.0f;
        if (lane < 8) {
            float Gi = gd[lane]      + (role ? bias_i : bf2f(ri));
            float Gf = gd[8 + lane]  + (role ? bias_f : bf2f(rf));
            float Gg = gd[16 + lane] + (role ? bias_g : bf2f(rg));
            float Go = gd[24 + lane] + (role ? bias_o : bf2f(ro));
            c_state = sigf(Gf) * c_state + sigf(Gi) * tanhfast(Gg);
            h_new = sigf(Go) * tanhfast(c_state);
        }

        // ---- publish: gather 8 h -> 2 u64 (4 odd-LSB bf16 each) ----
        u32 w0 = f2bfo(__shfl(h_new, (lane << 2)))     | (f2bfo(__shfl(h_new, (lane << 2) + 1)) << 16);
        u32 w1 = f2bfo(__shfl(h_new, (lane << 2) + 2)) | (f2bfo(__shfl(h_new, (lane << 2) + 3)) << 16);
        if (lane < 2) {
            u64 val = ((u64)w1 << 32) | w0;
            __hip_atomic_store(&hown[(size_t)s * 256 + (e0 >> 2) + lane], val,
                               __ATOMIC_RELAXED, __HIP_MEMORY_SCOPE_AGENT);
        }

        if (lane < 8) {
            if (role) {
                int rrow = d ? (1023 - s) : s;
                seq_out[(size_t)rrow * 2048 + d * 1024 + e0 + lane] = h_new;
            }
            if (s == 1023) {
                cm_out[d * 1024 + e0 + lane] = c_state;
                hs_out[d * 1024 + e0 + lane] = h_new;
            }
        }
    }
}

// ---------------------------------------------------------------------------
extern "C" void kernel_launch(void* const* d_in, const int* in_sizes, int n_in,
                              void* d_out, int out_size, void* d_ws, size_t ws_size,
                              hipStream_t stream) {
    (void)in_sizes; (void)n_in; (void)out_size; (void)ws_size;

    const float* x       = (const float*)d_in[0];
    const float* fw0_Wih = (const float*)d_in[1];
    const float* fw0_Whh = (const float*)d_in[2];
    const float* fw0_bih = (const float*)d_in[3];
    const float* fw0_bhh = (const float*)d_in[4];
    const float* fw1_Wih = (const float*)d_in[5];
    const float* fw1_Whh = (const float*)d_in[6];
    const float* fw1_bih = (const float*)d_in[7];
    const float* fw1_bhh = (const float*)d_in[8];
    const float* bw0_Wih = (const float*)d_in[9];
    const float* bw0_Whh = (const float*)d_in[10];
    const float* bw0_bih = (const float*)d_in[11];
    const float* bw0_bhh = (const float*)d_in[12];
    const float* bw1_Wih = (const float*)d_in[13];
    const float* bw1_Whh = (const float*)d_in[14];
    const float* bw1_bih = (const float*)d_in[15];
    const float* bw1_bhh = (const float*)d_in[16];

    char* ws = (char*)d_ws;
    u16* precomp = (u16*)ws;                      // [2][1024][4096] bf16 = 16 MB
    u64* htag0   = (u64*)(ws + (16 << 20));       // [2][1024][256]       =  4 MB
    u64* htag1   = (u64*)(ws + (20 << 20));       // [2][1024][256]       =  4 MB
    float* out   = (float*)d_out;

    hipMemsetAsync(htag0, 0, (size_t)8 << 20, stream);   // invalidate both

    dim3 g(8, 32);
    gemm_ih<<<g, 256, 0, stream>>>(x, fw0_Wih, fw0_bih, fw0_bhh, precomp, 768);
    gemm_ih<<<g, 256, 0, stream>>>(x, bw0_Wih, bw0_bih, bw0_bhh,
                                   precomp + (size_t)1024 * 4096, 768);

    lstm_fused<<<512, 64, 69760, stream>>>(
        fw0_Whh, bw0_Whh, fw1_Whh, bw1_Whh, fw1_Wih, bw1_Wih,
        fw1_bih, fw1_bhh, bw1_bih, bw1_bhh,
        precomp, htag0, htag1, out);
}

// Round 13
// 3221.707 us; speedup vs baseline: 1.1246x; 1.1246x over previous
//
#include <hip/hip_runtime.h>

typedef unsigned int u32;
typedef unsigned short u16;
typedef unsigned long long u64;
typedef __attribute__((ext_vector_type(8))) short v8s;   // 8 bf16
typedef __attribute__((ext_vector_type(4))) float v4f;

#define VALIDMASK 0x0001000100010001ULL

__device__ __forceinline__ float bf2f(u16 v) { return __uint_as_float(((u32)v) << 16); }
__device__ __forceinline__ u16 f2bf(float f) {
    u32 u = __float_as_uint(f);
    return (u16)((u + 0x7fffu + ((u >> 16) & 1u)) >> 16);   // RNE
}
// truncate-to-odd bf16: LSB always 1 (valid bit), |err| <= 1 ulp
__device__ __forceinline__ u32 f2bfo(float f) { return (__float_as_uint(f) >> 16) | 1u; }
__device__ __forceinline__ float sigf(float x) { return 1.0f / (1.0f + __expf(-x)); }
__device__ __forceinline__ float tanhfast(float x) {
    float e = __expf(2.0f * x);
    return 1.0f - 2.0f / (e + 1.0f);
}
__device__ __forceinline__ v8s pack8(v4f a, v4f b) {
    v8s r;
    r[0] = (short)f2bf(a[0]); r[1] = (short)f2bf(a[1]);
    r[2] = (short)f2bf(a[2]); r[3] = (short)f2bf(a[3]);
    r[4] = (short)f2bf(b[0]); r[5] = (short)f2bf(b[1]);
    r[6] = (short)f2bf(b[2]); r[7] = (short)f2bf(b[3]);
    return r;
}

// ---------------------------------------------------------------------------
// GEMM: out[t][j] = sum_k A[t][k]*W[j][k] + bih[j] + bhh[j]. fp32 in, bf16 out.
// Layer-0 input projections only (K=768).
// ---------------------------------------------------------------------------
__global__ __launch_bounds__(256) void gemm_ih(
    const float* __restrict__ A, const float* __restrict__ W,
    const float* __restrict__ bih, const float* __restrict__ bhh,
    u16* __restrict__ out, int K)
{
    __shared__ u16 As[128][40];
    __shared__ u16 Bs[128][40];
    const int tm = blockIdx.x, tn = blockIdx.y;
    const int tid = threadIdx.x;
    const int lane = tid & 63;
    const int wv = tid >> 6;
    const int wm = wv >> 1, wn = wv & 1;
    const int fr = lane & 15, fq = lane >> 4;

    v4f acc[4][4] = {};

    for (int kt = 0; kt < K; kt += 32) {
#pragma unroll
        for (int it = 0; it < 2; ++it) {
            int q = tid + it * 256;
            int r = q >> 2;
            int c8 = (q & 3) * 8;
            const float* pa = &A[(size_t)(tm * 128 + r) * K + kt + c8];
            const float* pw = &W[(size_t)(tn * 128 + r) * K + kt + c8];
            *(v8s*)&As[r][c8] = pack8(*(const v4f*)pa, *(const v4f*)(pa + 4));
            *(v8s*)&Bs[r][c8] = pack8(*(const v4f*)pw, *(const v4f*)(pw + 4));
        }
        __syncthreads();
        v8s af[4], bfr[4];
#pragma unroll
        for (int mi = 0; mi < 4; ++mi)
            af[mi] = *(const v8s*)&As[wm * 64 + mi * 16 + fr][fq * 8];
#pragma unroll
        for (int ni = 0; ni < 4; ++ni)
            bfr[ni] = *(const v8s*)&Bs[wn * 64 + ni * 16 + fr][fq * 8];
#pragma unroll
        for (int mi = 0; mi < 4; ++mi)
#pragma unroll
            for (int ni = 0; ni < 4; ++ni)
                acc[mi][ni] = __builtin_amdgcn_mfma_f32_16x16x32_bf16(af[mi], bfr[ni], acc[mi][ni], 0, 0, 0);
        __syncthreads();
    }

#pragma unroll
    for (int ni = 0; ni < 4; ++ni) {
        int col = tn * 128 + wn * 64 + ni * 16 + fr;
        float bias = bih[col] + bhh[col];
#pragma unroll
        for (int mi = 0; mi < 4; ++mi)
#pragma unroll
            for (int j = 0; j < 4; ++j) {
                int row = tm * 128 + wm * 64 + mi * 16 + fq * 4 + j;
                out[(size_t)row * 4096 + col] = f2bf(acc[mi][ni][j] + bias);
            }
    }
}

// ---------------------------------------------------------------------------
// Fused persistent bidirectional 2-layer LSTM scan. 512 WGs x 64 threads
// (1 wave per WG, no barriers). role = bid>>8 (0:L0, 1:L1), d = (bid>>7)&1,
// wg = bid&127, e0 = wg*8 (8 h-elements = 32 Whh rows).
// Whh: 256 VGPRs of pre-packed 16x16x32 A-fragments. L1's Wih1: LDS in
// fragment-contiguous layout off = c*2048+q*512+t*256+r0*16 (conflict-free).
// L1 PIPELINE: Wih1 @ h0[s+1] is computed AFTER publishing h1[s] into a
// carried accumulator (wacc) — it runs in the fabric-latency window while
// peers' h1[s] propagates, so the critical loop is poll->Whh->gates->publish
// for BOTH layers. Broadcast: 4 odd-LSB bf16/u64 (LSB=valid), relaxed agent
// atomics; h staging 8B-stride ds_writes (conflict-free).
// ---------------------------------------------------------------------------
__global__ __launch_bounds__(64, 1) void lstm_fused(
    const float* __restrict__ fw0_Whh, const float* __restrict__ bw0_Whh,
    const float* __restrict__ fw1_Whh, const float* __restrict__ bw1_Whh,
    const float* __restrict__ fw1_Wih, const float* __restrict__ bw1_Wih,
    const float* __restrict__ fw1_bih, const float* __restrict__ fw1_bhh,
    const float* __restrict__ bw1_bih, const float* __restrict__ bw1_bhh,
    const u16*  __restrict__ precomp0,   // [2][1024][4096] bf16
    u64* htag0,                          // [2][1024][256]
    u64* htag1,                          // [2][1024][256]
    float* __restrict__ out)             // d_out base
{
    extern __shared__ char smem[];       // [0,64K): Wih frags (L1)
    char* hA = smem + 65536;             // 2 KB own-layer h
    char* hB = smem + 65536 + 2048;      // 2 KB h0 input (L1)
    float* gd = (float*)(smem + 65536 + 4096);   // 32 gate sums

    const int lane = threadIdx.x;
    const int bid = blockIdx.x;
    const int role = bid >> 8;
    const int sub = bid & 255;
    const int d = sub >> 7;
    const int wg = sub & 127;
    const int e0 = wg << 3;
    const int q16 = (lane >> 4) << 4;    // B-frag byte offset within 64B block

    const float* __restrict__ Whh =
        role ? (d ? bw1_Whh : fw1_Whh) : (d ? bw0_Whh : fw0_Whh);

    // ---- Whh -> 64 A-fragments in registers (2 tiles x 32 K-chunks) ----
    v8s awf0[32], awf1[32];
    {
        int r0 = lane & 15, r1 = r0 + 16;
        int kq = (lane >> 4) << 3;
        const float* p0 = &Whh[(size_t)((r0 >> 3) * 1024 + e0 + (r0 & 7)) * 1024 + kq];
        const float* p1 = &Whh[(size_t)((r1 >> 3) * 1024 + e0 + (r1 & 7)) * 1024 + kq];
#pragma unroll
        for (int c = 0; c < 32; ++c) {
            awf0[c] = pack8(*(const v4f*)(p0 + 32 * c), *(const v4f*)(p0 + 32 * c + 4));
            awf1[c] = pack8(*(const v4f*)(p1 + 32 * c), *(const v4f*)(p1 + 32 * c + 4));
        }
    }

    // ---- L1: Wih1 -> LDS fragment-contiguous (both column halves); biases ----
    float bias_i = 0.f, bias_f = 0.f, bias_g = 0.f, bias_o = 0.f;
    if (role) {
        const float* __restrict__ Wih = d ? bw1_Wih : fw1_Wih;
        for (int i = 0; i < 32; ++i) {
            const float* prow = &Wih[(size_t)((i >> 3) * 1024 + e0 + (i & 7)) * 1024];
            int base = ((lane & 3) << 9) + ((i >> 4) << 8) + ((i & 15) << 4);
            const float* p0 = prow + lane * 8;
            const float* p1 = prow + 512 + lane * 8;
            *(v8s*)(smem + ((lane >> 2) << 11) + base) =
                pack8(*(const v4f*)p0, *(const v4f*)(p0 + 4));
            *(v8s*)(smem + ((16 + (lane >> 2)) << 11) + base) =
                pack8(*(const v4f*)p1, *(const v4f*)(p1 + 4));
        }
        if (lane < 8) {
            const float* bi = d ? bw1_bih : fw1_bih;
            const float* bh = d ? bw1_bhh : fw1_bhh;
            bias_i = bi[e0 + lane]        + bh[e0 + lane];
            bias_f = bi[1024 + e0 + lane] + bh[1024 + e0 + lane];
            bias_g = bi[2048 + e0 + lane] + bh[2048 + e0 + lane];
            bias_o = bi[3072 + e0 + lane] + bh[3072 + e0 + lane];
        }
    }

    u64* hown = (role ? htag1 : htag0) + (size_t)d * 1024 * 256;
    u64* hin  = htag0 + (size_t)d * 1024 * 256;
    float* cm_out = out + role * 2048;
    float* hs_out = out + 4096 + role * 2048;
    float* seq_out = out + 8192;                 // [1024][2048], L1 writes

    float c_state = 0.0f;                        // lanes 0..7 own elem e0+lane
    v4f wacc0 = {0.f,0.f,0.f,0.f}, wacc1 = {0.f,0.f,0.f,0.f};
    const int fb = ((lane >> 4) << 9) + ((lane & 15) << 4);  // q*512+r0*16

    // ---- L1 prologue: prefetch h0[0] and compute Wih dot into wacc ----
    if (role) {
        u64* p = hin + lane;
        u64 a, b, c2, d2;
        for (;;) {
            a  = __hip_atomic_load(&p[0],   __ATOMIC_RELAXED, __HIP_MEMORY_SCOPE_AGENT);
            b  = __hip_atomic_load(&p[64],  __ATOMIC_RELAXED, __HIP_MEMORY_SCOPE_AGENT);
            c2 = __hip_atomic_load(&p[128], __ATOMIC_RELAXED, __HIP_MEMORY_SCOPE_AGENT);
            d2 = __hip_atomic_load(&p[192], __ATOMIC_RELAXED, __HIP_MEMORY_SCOPE_AGENT);
            if ((((a & b) & (c2 & d2)) & VALIDMASK) == VALIDMASK) break;
            __builtin_amdgcn_s_sleep(1);
        }
        *(u64*)(hB + (lane << 3))        = a;
        *(u64*)(hB + (lane << 3) + 512)  = b;
        *(u64*)(hB + (lane << 3) + 1024) = c2;
        *(u64*)(hB + (lane << 3) + 1536) = d2;
        asm volatile("s_waitcnt lgkmcnt(0)" ::: "memory");
#pragma unroll
        for (int c = 0; c < 32; c += 2) {
            v8s b0 = *(const v8s*)(hB + (c << 6) + q16);
            v8s b1 = *(const v8s*)(hB + ((c + 1) << 6) + q16);
            v8s a00 = *(const v8s*)(smem + (c << 11) + fb);
            v8s a01 = *(const v8s*)(smem + (c << 11) + fb + 256);
            v8s a10 = *(const v8s*)(smem + ((c + 1) << 11) + fb);
            v8s a11 = *(const v8s*)(smem + ((c + 1) << 11) + fb + 256);
            wacc0 = __builtin_amdgcn_mfma_f32_16x16x32_bf16(a00, b0, wacc0, 0, 0, 0);
            wacc1 = __builtin_amdgcn_mfma_f32_16x16x32_bf16(a01, b0, wacc1, 0, 0, 0);
            wacc0 = __builtin_amdgcn_mfma_f32_16x16x32_bf16(a10, b1, wacc0, 0, 0, 0);
            wacc1 = __builtin_amdgcn_mfma_f32_16x16x32_bf16(a11, b1, wacc1, 0, 0, 0);
        }
    }

    for (int s = 0; s < 1024; ++s) {
        v4f acc0a = {0.f,0.f,0.f,0.f}, acc0b = {0.f,0.f,0.f,0.f};
        v4f acc1a = {0.f,0.f,0.f,0.f}, acc1b = {0.f,0.f,0.f,0.f};

        // L0: prefetch precomp row early (hides under poll)
        u16 ri = 0, rf = 0, rg = 0, ro = 0;
        if (!role && lane < 8) {
            int sx = d ? (1023 - s) : s;
            const u16* pr = precomp0 + ((size_t)d * 1024 + sx) * 4096 + e0 + lane;
            ri = pr[0]; rf = pr[1024]; rg = pr[2048]; ro = pr[3072];
        }

        if (s > 0) {  // ---- Whh @ h_own[s-1] (the critical recurrence) ----
            u64* p = hown + (size_t)(s - 1) * 256 + lane;
            u64 a, b, c2, d2;
            for (;;) {
                a  = __hip_atomic_load(&p[0],   __ATOMIC_RELAXED, __HIP_MEMORY_SCOPE_AGENT);
                b  = __hip_atomic_load(&p[64],  __ATOMIC_RELAXED, __HIP_MEMORY_SCOPE_AGENT);
                c2 = __hip_atomic_load(&p[128], __ATOMIC_RELAXED, __HIP_MEMORY_SCOPE_AGENT);
                d2 = __hip_atomic_load(&p[192], __ATOMIC_RELAXED, __HIP_MEMORY_SCOPE_AGENT);
                if ((((a & b) & (c2 & d2)) & VALIDMASK) == VALIDMASK) break;
                __builtin_amdgcn_s_sleep(1);
            }
            __builtin_amdgcn_s_setprio(1);
            *(u64*)(hA + (lane << 3))        = a;
            *(u64*)(hA + (lane << 3) + 512)  = b;
            *(u64*)(hA + (lane << 3) + 1024) = c2;
            *(u64*)(hA + (lane << 3) + 1536) = d2;
            asm volatile("s_waitcnt lgkmcnt(0)" ::: "memory");
#pragma unroll
            for (int c = 0; c < 32; c += 2) {
                v8s b0 = *(const v8s*)(hA + (c << 6) + q16);
                v8s b1 = *(const v8s*)(hA + ((c + 1) << 6) + q16);
                acc0a = __builtin_amdgcn_mfma_f32_16x16x32_bf16(awf0[c], b0, acc0a, 0, 0, 0);
                acc1a = __builtin_amdgcn_mfma_f32_16x16x32_bf16(awf1[c], b0, acc1a, 0, 0, 0);
                acc0b = __builtin_amdgcn_mfma_f32_16x16x32_bf16(awf0[c + 1], b1, acc0b, 0, 0, 0);
                acc1b = __builtin_amdgcn_mfma_f32_16x16x32_bf16(awf1[c + 1], b1, acc1b, 0, 0, 0);
            }
            __builtin_amdgcn_s_setprio(0);
        }

        // ---- combine (+ pipelined Wih contribution for L1); dump gates ----
        v4f acc0 = acc0a + acc0b + wacc0;
        v4f acc1 = acc1a + acc1b + wacc1;
        if ((lane & 15) == 0) {
            int rbase = (lane >> 4) << 2;        // 0,4,8,12
            *(v4f*)&gd[rbase]      = acc0;       // rows 0..15  (i, f)
            *(v4f*)&gd[16 + rbase] = acc1;       // rows 16..31 (g, o)
        }
        asm volatile("s_waitcnt lgkmcnt(0)" ::: "memory");

        float h_new = 0.0f;
        if (lane < 8) {
            float Gi = gd[lane]      + (role ? bias_i : bf2f(ri));
            float Gf = gd[8 + lane]  + (role ? bias_f : bf2f(rf));
            float Gg = gd[16 + lane] + (role ? bias_g : bf2f(rg));
            float Go = gd[24 + lane] + (role ? bias_o : bf2f(ro));
            c_state = sigf(Gf) * c_state + sigf(Gi) * tanhfast(Gg);
            h_new = sigf(Go) * tanhfast(c_state);
        }

        // ---- publish ASAP: gather 8 h -> 2 u64 (4 odd-LSB bf16 each) ----
        u32 w0 = f2bfo(__shfl(h_new, (lane << 2)))     | (f2bfo(__shfl(h_new, (lane << 2) + 1)) << 16);
        u32 w1 = f2bfo(__shfl(h_new, (lane << 2) + 2)) | (f2bfo(__shfl(h_new, (lane << 2) + 3)) << 16);
        if (lane < 2) {
            u64 val = ((u64)w1 << 32) | w0;
            __hip_atomic_store(&hown[(size_t)s * 256 + (e0 >> 2) + lane], val,
                               __ATOMIC_RELAXED, __HIP_MEMORY_SCOPE_AGENT);
        }

        if (lane < 8) {
            if (role) {
                int rrow = d ? (1023 - s) : s;
                seq_out[(size_t)rrow * 2048 + d * 1024 + e0 + lane] = h_new;
            }
            if (s == 1023) {
                cm_out[d * 1024 + e0 + lane] = c_state;
                hs_out[d * 1024 + e0 + lane] = h_new;
            }
        }

        // ---- L1: prefetch h0[s+1] + Wih dot into wacc (off critical path:
        //      runs while peers' h1[s] propagates through the fabric) ----
        if (role && s < 1023) {
            wacc0 = (v4f){0.f,0.f,0.f,0.f};
            wacc1 = (v4f){0.f,0.f,0.f,0.f};
            u64* p = hin + (size_t)(s + 1) * 256 + lane;
            u64 a, b, c2, d2;
            for (;;) {
                a  = __hip_atomic_load(&p[0],   __ATOMIC_RELAXED, __HIP_MEMORY_SCOPE_AGENT);
                b  = __hip_atomic_load(&p[64],  __ATOMIC_RELAXED, __HIP_MEMORY_SCOPE_AGENT);
                c2 = __hip_atomic_load(&p[128], __ATOMIC_RELAXED, __HIP_MEMORY_SCOPE_AGENT);
                d2 = __hip_atomic_load(&p[192], __ATOMIC_RELAXED, __HIP_MEMORY_SCOPE_AGENT);
                if ((((a & b) & (c2 & d2)) & VALIDMASK) == VALIDMASK) break;
                __builtin_amdgcn_s_sleep(1);
            }
            *(u64*)(hB + (lane << 3))        = a;
            *(u64*)(hB + (lane << 3) + 512)  = b;
            *(u64*)(hB + (lane << 3) + 1024) = c2;
            *(u64*)(hB + (lane << 3) + 1536) = d2;
            asm volatile("s_waitcnt lgkmcnt(0)" ::: "memory");
#pragma unroll
            for (int c = 0; c < 32; c += 2) {
                v8s b0 = *(const v8s*)(hB + (c << 6) + q16);
                v8s b1 = *(const v8s*)(hB + ((c + 1) << 6) + q16);
                v8s a00 = *(const v8s*)(smem + (c << 11) + fb);
                v8s a01 = *(const v8s*)(smem + (c << 11) + fb + 256);
                v8s a10 = *(const v8s*)(smem + ((c + 1) << 11) + fb);
                v8s a11 = *(const v8s*)(smem + ((c + 1) << 11) + fb + 256);
                wacc0 = __builtin_amdgcn_mfma_f32_16x16x32_bf16(a00, b0, wacc0, 0, 0, 0);
                wacc1 = __builtin_amdgcn_mfma_f32_16x16x32_bf16(a01, b0, wacc1, 0, 0, 0);
                wacc0 = __builtin_amdgcn_mfma_f32_16x16x32_bf16(a10, b1, wacc0, 0, 0, 0);
                wacc1 = __builtin_amdgcn_mfma_f32_16x16x32_bf16(a11, b1, wacc1, 0, 0, 0);
            }
        }
    }
}

// ---------------------------------------------------------------------------
extern "C" void kernel_launch(void* const* d_in, const int* in_sizes, int n_in,
                              void* d_out, int out_size, void* d_ws, size_t ws_size,
                              hipStream_t stream) {
    (void)in_sizes; (void)n_in; (void)out_size; (void)ws_size;

    const float* x       = (const float*)d_in[0];
    const float* fw0_Wih = (const float*)d_in[1];
    const float* fw0_Whh = (const float*)d_in[2];
    const float* fw0_bih = (const float*)d_in[3];
    const float* fw0_bhh = (const float*)d_in[4];
    const float* fw1_Wih = (const float*)d_in[5];
    const float* fw1_Whh = (const float*)d_in[6];
    const float* fw1_bih = (const float*)d_in[7];
    const float* fw1_bhh = (const float*)d_in[8];
    const float* bw0_Wih = (const float*)d_in[9];
    const float* bw0_Whh = (const float*)d_in[10];
    const float* bw0_bih = (const float*)d_in[11];
    const float* bw0_bhh = (const float*)d_in[12];
    const float* bw1_Wih = (const float*)d_in[13];
    const float* bw1_Whh = (const float*)d_in[14];
    const float* bw1_bih = (const float*)d_in[15];
    const float* bw1_bhh = (const float*)d_in[16];

    char* ws = (char*)d_ws;
    u16* precomp = (u16*)ws;                      // [2][1024][4096] bf16 = 16 MB
    u64* htag0   = (u64*)(ws + (16 << 20));       // [2][1024][256]       =  4 MB
    u64* htag1   = (u64*)(ws + (20 << 20));       // [2][1024][256]       =  4 MB
    float* out   = (float*)d_out;

    hipMemsetAsync(htag0, 0, (size_t)8 << 20, stream);   // invalidate both

    dim3 g(8, 32);
    gemm_ih<<<g, 256, 0, stream>>>(x, fw0_Wih, fw0_bih, fw0_bhh, precomp, 768);
    gemm_ih<<<g, 256, 0, stream>>>(x, bw0_Wih, bw0_bih, bw0_bhh,
                                   precomp + (size_t)1024 * 4096, 768);

    lstm_fused<<<512, 64, 69760, stream>>>(
        fw0_Whh, bw0_Whh, fw1_Whh, bw1_Whh, fw1_Wih, bw1_Wih,
        fw1_bih, fw1_bhh, bw1_bih, bw1_bhh,
        precomp, htag0, htag1, out);
}